// Round 12
// baseline (897.413 us; speedup 1.0000x reference)
//
#include <hip/hip_runtime.h>
#include <hip/hip_cooperative_groups.h>
#include <hip/hip_bf16.h>
#include <hip/hip_fp16.h>

namespace cg = cooperative_groups;

#define B_    512
#define NI    1152
#define NO    10
#define BT    16
#define NBT   32           // B_/BT
#define NC    24           // chunks (8 XCD x 3)
#define NCH   48           // n per chunk
#define RNDS  6
#define RN    8            // n per staged round

#define WBUF_US 12288      // W round image: 24 granules * 512 us
#define XBUF_US 1024       // x round image: 8 n * 128 us
#define BUF_US  13312      // W + x (26,624 B per buffer)

typedef __attribute__((ext_vector_type(8))) short bf16x8;
typedef __attribute__((ext_vector_type(4))) float f32x4;
typedef __attribute__((ext_vector_type(8))) unsigned short u16x8;

// workspace element counts
#define SPART_H    ((size_t)NC * NBT * NO * 256)      // 1,966,080 halfs (3.93 MB)
#define OUTSUM_F32 ((size_t)NBT * NO * 256)           //    81,920 f32  (0.33 MB)
#define XB_US      ((size_t)NBT * NC * RNDS * XBUF_US)// 4,718,592 us   (9.44 MB)
#define WB_US      ((size_t)NC * RNDS * WBUF_US)      // 1,769,472 us   (3.54 MB)

__device__ inline unsigned short f2bf(float f) {
    __hip_bfloat16 h = __float2bfloat16(f);
    return *reinterpret_cast<unsigned short*>(&h);
}

__device__ inline void gld_lds16(const void* g, void* lds) {
    __builtin_amdgcn_global_load_lds(
        (const __attribute__((address_space(1))) void*)g,
        (__attribute__((address_space(3))) void*)lds, 16, 0, 0);
}

// ---- cvt helpers (round-10 logic) ---------------------------------------
__device__ __forceinline__ void cvt_x_one(int t, const float* __restrict__ x,
                                          unsigned short* __restrict__ xb) {
    const int m   = t & 127;
    const int img = t >> 7;                    // (bt*NC+nc)*6+r
    const int nl  = m >> 4, bl = m & 15;
    const int r   = img % RNDS;
    const int bc  = img / RNDS;
    const int nc  = bc % NC, bt = bc / NC;
    const int b   = bt * BT + bl;
    const int n   = nc * NCH + r * RN + nl;
    const float* src = x + ((size_t)b * NI + n) * 8;
    float4 v0 = *reinterpret_cast<const float4*>(src);
    float4 v1 = *reinterpret_cast<const float4*>(src + 4);
    u16x8 u = { f2bf(v0.x), f2bf(v0.y), f2bf(v0.z), f2bf(v0.w),
                f2bf(v1.x), f2bf(v1.y), f2bf(v1.z), f2bf(v1.w) };
    *reinterpret_cast<u16x8*>(xb + (size_t)t * 8) = u;
}

__device__ __forceinline__ void cvt_w_one(int t, const float* __restrict__ w,
                                          unsigned short* __restrict__ wb) {
    const int lane = t & 63;
    const int gs   = (t >> 6) % 24;
    const int img  = t / 1536;                 // nc*6+r
    const int hi   = lane >> 4, d = lane & 15;
    const int nl   = gs / 3, oq = gs % 3;
    const int r    = img % RNDS, nc = img / RNDS;
    const int o    = oq * 4 + hi;
    const int n    = nc * NCH + r * RN + nl;
    u16x8 u = {0,0,0,0,0,0,0,0};
    if (o < NO) {
        const float* src = w + ((size_t)o * NI + n) * 128 + d * 8;
        float4 v0 = *reinterpret_cast<const float4*>(src);
        float4 v1 = *reinterpret_cast<const float4*>(src + 4);
        u = (u16x8){ f2bf(v0.x), f2bf(v0.y), f2bf(v0.z), f2bf(v0.w),
                     f2bf(v1.x), f2bf(v1.y), f2bf(v1.z), f2bf(v1.w) };
    }
    *reinterpret_cast<u16x8*>(wb + (size_t)t * 8) = u;
}

// ---- per-round compute core (round-10 logic, verbatim) ------------------
template<bool UNIFORM>
__device__ __forceinline__ void round_compute(
    const unsigned short* sb,       // LDS buffer: W at 0, x at WBUF_US
    const f32x4* outf, f32x4* sacc, int w, int l, int b16, int hi)
{
    #pragma unroll 1
    for (int i = 0; i < 2; ++i) {
        const int nl = w * 2 + i;
        bf16x8 bv = *reinterpret_cast<const bf16x8*>(
            &sb[WBUF_US + nl * 128 + b16 * 8]);
        bf16x8 bvt[4];
        #pragma unroll
        for (int t = 0; t < 4; ++t)
            bvt[t] = (hi == t) ? bv : (bf16x8){0,0,0,0,0,0,0,0};

        if constexpr (UNIFORM) {
            #pragma unroll
            for (int oq = 0; oq < 3; ++oq) {
                bf16x8 av = *reinterpret_cast<const bf16x8*>(
                    &sb[(nl * 3 + oq) * 512 + l * 8]);
                const int tmax = (oq < 2) ? 4 : 2;
                #pragma unroll
                for (int t = 0; t < tmax; ++t)
                    sacc[oq * 4 + t] = __builtin_amdgcn_mfma_f32_16x16x32_bf16(
                        av, bvt[t], sacc[oq * 4 + t], 0, 0, 0);
            }
        } else {
            f32x4 xh[NO];
            float lg[NO];
            #pragma unroll
            for (int oq = 0; oq < 3; ++oq) {
                bf16x8 av = *reinterpret_cast<const bf16x8*>(
                    &sb[(nl * 3 + oq) * 512 + l * 8]);
                const int tmax = (oq < 2) ? 4 : 2;
                #pragma unroll
                for (int t = 0; t < tmax; ++t) {
                    const int o = oq * 4 + t;
                    xh[o] = __builtin_amdgcn_mfma_f32_16x16x32_bf16(
                        av, bvt[t], (f32x4){0.f, 0.f, 0.f, 0.f}, 0, 0, 0);
                    float pp = outf[o][0] * xh[o][0];
                    pp = fmaf(outf[o][1], xh[o][1], pp);
                    pp = fmaf(outf[o][2], xh[o][2], pp);
                    pp = fmaf(outf[o][3], xh[o][3], pp);
                    pp += __shfl_xor(pp, 16, 64);
                    pp += __shfl_xor(pp, 32, 64);
                    lg[o] = pp;
                }
            }
            float sum = 0.f;
            #pragma unroll
            for (int o = 0; o < NO; ++o) { lg[o] = __expf(lg[o]); sum += lg[o]; }
            const float rs = __builtin_amdgcn_rcpf(sum);
            #pragma unroll
            for (int o = 0; o < NO; ++o) {
                const float cc = lg[o] * rs;
                sacc[o][0] = fmaf(cc, xh[o][0], sacc[o][0]);
                sacc[o][1] = fmaf(cc, xh[o][1], sacc[o][1]);
                sacc[o][2] = fmaf(cc, xh[o][2], sacc[o][2]);
                sacc[o][3] = fmaf(cc, xh[o][3], sacc[o][3]);
            }
        }
    }
}

// ---- epilogue: cross-wave fp16-packed reduce + coalesced store ----------
__device__ __forceinline__ void iter_epilogue(
    uint2 (*red)[NO * 64], const f32x4* sacc, float sc,
    int w, int l, int tid, unsigned short* base)
{
    #pragma unroll
    for (int o = 0; o < NO; ++o) {
        __half2 h01 = __floats2half2_rn(sacc[o][0] * sc, sacc[o][1] * sc);
        __half2 h23 = __floats2half2_rn(sacc[o][2] * sc, sacc[o][3] * sc);
        red[w][o * 64 + l] =
            make_uint2(*reinterpret_cast<unsigned int*>(&h01),
                       *reinterpret_cast<unsigned int*>(&h23));
    }
    __syncthreads();
    for (int g = tid; g < NO * 64; g += 256) {
        uint2 a0 = red[0][g], a1 = red[1][g], a2 = red[2][g], a3 = red[3][g];
        auto h2f2 = [](unsigned int u) {
            __half2 h = *reinterpret_cast<__half2*>(&u);
            return __half22float2(h);
        };
        float2 lo = h2f2(a0.x), l1 = h2f2(a1.x), l2 = h2f2(a2.x), l3 = h2f2(a3.x);
        float2 ho = h2f2(a0.y), h1 = h2f2(a1.y), h2 = h2f2(a2.y), h3 = h2f2(a3.y);
        float2 sl = { (lo.x + l1.x) + (l2.x + l3.x), (lo.y + l1.y) + (l2.y + l3.y) };
        float2 sh = { (ho.x + h1.x) + (h2.x + h3.x), (ho.y + h1.y) + (h2.y + h3.y) };
        __half2 p01 = __floats2half2_rn(sl.x, sl.y);
        __half2 p23 = __floats2half2_rn(sh.x, sh.y);
        *reinterpret_cast<uint2*>(base + (size_t)g * 4) =
            make_uint2(*reinterpret_cast<unsigned int*>(&p01),
                       *reinterpret_cast<unsigned int*>(&p23));
    }
}

// ---- squash body (round-10 logic) ---------------------------------------
template<int MODE>
__device__ __forceinline__ void squash_body(
    float* sq, const unsigned short* __restrict__ s_part,
    float* __restrict__ outsum, float* __restrict__ dout, int bo, int t)
{
    float s = 0.f;
    #pragma unroll 4
    for (int nc = 0; nc < NC; ++nc) {
        __half h = *reinterpret_cast<const __half*>(
            s_part + ((size_t)nc * NBT * NO + bo) * 256 + t);
        s += __half2float(h);
    }
    float n2 = s * s;
    n2 += __shfl_xor(n2, 1, 64);
    n2 += __shfl_xor(n2, 2, 64);
    sq[t] = n2;
    __syncthreads();
    const int base = t & 63;
    n2 = (sq[base] + sq[64 + base]) + (sq[128 + base] + sq[192 + base]);

    const float norm  = sqrtf(n2);
    const float scale = n2 / ((1.f + n2) * (norm + 1e-8f));
    const float v = scale * s;

    if constexpr (MODE == 0) {
        outsum[(size_t)bo * 256 + t] = v;
    } else if constexpr (MODE == 1) {
        outsum[(size_t)bo * 256 + t] += v;
    } else {
        const int bt = bo / NO, o = bo - bt * NO;
        const int b16 = (t >> 2) & 15, hi = t >> 6, q = t & 3;
        dout[((size_t)(bt * BT + b16) * NO + o) * 16 + hi * 4 + q] = v;
    }
    __syncthreads();
}

// ======================= standalone fallback kernels =====================
__global__ __launch_bounds__(256) void cvt_xw(
    const float* __restrict__ x, const float* __restrict__ w,
    unsigned short* __restrict__ xb, unsigned short* __restrict__ wb)
{
    const int blk = blockIdx.x;
    if (blk < 2304) cvt_x_one(blk * 256 + threadIdx.x, x, xb);
    else            cvt_w_one((blk - 2304) * 256 + threadIdx.x, w, wb);
}

union LdsBig {
    unsigned short stage[2 * BUF_US];   // 53,248 B (double-buffered)
    uint2 red[4][NO * 64];
};

template<bool UNIFORM>
__global__ __launch_bounds__(256, 3) void caps_iter(
    const unsigned short* __restrict__ xb,
    const unsigned short* __restrict__ wb,
    const float* __restrict__ outsum,
    unsigned short* __restrict__ s_part)
{
    __shared__ LdsBig lds;
    const int tid = threadIdx.x;
    const int w = tid >> 6, l = tid & 63, b16 = l & 15, hi = l >> 4;
    const int blk = blockIdx.x;
    const int xcd = blk & 7, idx = blk >> 3;
    const int nc  = xcd * 3 + (idx >> 5);
    const int bt  = idx & 31;

    const unsigned short* wsrc = wb + (size_t)nc * (RNDS * WBUF_US);
    const unsigned short* xsrc = xb + ((size_t)bt * NC + nc) * (RNDS * XBUF_US);

    auto stage = [&](int r, int kbuf) {
        const unsigned short* wr = wsrc + (size_t)r * WBUF_US;
        char* dst = (char*)lds.stage + kbuf * (BUF_US * 2);
        #pragma unroll
        for (int k = 0; k < 6; ++k)
            gld_lds16(wr + (k * 256 + tid) * 8, dst + (k * 256 + tid) * 16);
        if (tid < 128)
            gld_lds16(xsrc + (size_t)r * XBUF_US + tid * 8,
                      dst + WBUF_US * 2 + tid * 16);
    };

    f32x4 outf[NO];
    if constexpr (!UNIFORM) {
        #pragma unroll
        for (int o = 0; o < NO; ++o)
            outf[o] = *reinterpret_cast<const f32x4*>(
                outsum + (((size_t)bt * NO + o) * 64 + l) * 4);
    }
    f32x4 sacc[NO];
    #pragma unroll
    for (int o = 0; o < NO; ++o) sacc[o] = (f32x4){0.f, 0.f, 0.f, 0.f};

    stage(0, 0);
    asm volatile("s_waitcnt vmcnt(0)" ::: "memory");
    __syncthreads();

    #pragma unroll 1
    for (int r = 0; r < RNDS; ++r) {
        if (r + 1 < RNDS) stage(r + 1, (r + 1) & 1);
        round_compute<UNIFORM>(lds.stage + (r & 1) * BUF_US, outf, sacc,
                               w, l, b16, hi);
        asm volatile("s_waitcnt vmcnt(0)" ::: "memory");
        __syncthreads();
    }

    iter_epilogue(lds.red, sacc, UNIFORM ? 0.1f : 1.0f, w, l, tid,
                  s_part + ((size_t)nc * NBT + bt) * 2560);
}

template<int MODE>
__global__ __launch_bounds__(256) void caps_squash(
    const unsigned short* __restrict__ s_part,
    float* __restrict__ outsum, float* __restrict__ dout)
{
    __shared__ float sq[256];
    squash_body<MODE>(sq, s_part, outsum, dout, blockIdx.x, threadIdx.x);
}

// ======================= fused cooperative kernel ========================
union LdsCoop {
    unsigned short stage[BUF_US];       // 26,624 B (single buffer)
    uint2 red[4][NO * 64];              // 20,480 B
    float sq[256];
};

template<bool UNIFORM>
__device__ __forceinline__ void iter_phase_coop(LdsCoop& lds,
    const unsigned short* __restrict__ xb,
    const unsigned short* __restrict__ wb,
    const float* __restrict__ outsum,
    unsigned short* __restrict__ s_part, int tid, int blk)
{
    const int w = tid >> 6, l = tid & 63, b16 = l & 15, hi = l >> 4;
    const int xcd = blk & 7, idx = blk >> 3;
    const int nc  = xcd * 3 + (idx >> 5);
    const int bt  = idx & 31;

    const unsigned short* wsrc = wb + (size_t)nc * (RNDS * WBUF_US);
    const unsigned short* xsrc = xb + ((size_t)bt * NC + nc) * (RNDS * XBUF_US);

    f32x4 outf[NO];
    if constexpr (!UNIFORM) {
        #pragma unroll
        for (int o = 0; o < NO; ++o)
            outf[o] = *reinterpret_cast<const f32x4*>(
                outsum + (((size_t)bt * NO + o) * 64 + l) * 4);
    }
    f32x4 sacc[NO];
    #pragma unroll
    for (int o = 0; o < NO; ++o) sacc[o] = (f32x4){0.f, 0.f, 0.f, 0.f};

    #pragma unroll 1
    for (int r = 0; r < RNDS; ++r) {
        const unsigned short* wr = wsrc + (size_t)r * WBUF_US;
        #pragma unroll
        for (int k = 0; k < 6; ++k)
            gld_lds16(wr + (k * 256 + tid) * 8,
                      (char*)lds.stage + (k * 256 + tid) * 16);
        if (tid < 128)
            gld_lds16(xsrc + (size_t)r * XBUF_US + tid * 8,
                      (char*)lds.stage + WBUF_US * 2 + tid * 16);
        asm volatile("s_waitcnt vmcnt(0)" ::: "memory");
        __syncthreads();

        round_compute<UNIFORM>(lds.stage, outf, sacc, w, l, b16, hi);
        __syncthreads();   // all reads done before next round overwrites
    }

    iter_epilogue(lds.red, sacc, UNIFORM ? 0.1f : 1.0f, w, l, tid,
                  s_part + ((size_t)nc * NBT + bt) * 2560);
}

__global__ __launch_bounds__(256, 3) void caps_all(
    const float* __restrict__ x, const float* __restrict__ w,
    unsigned short* __restrict__ xb, unsigned short* __restrict__ wb,
    unsigned short* __restrict__ s_part, float* __restrict__ outsum,
    float* __restrict__ dout)
{
    __shared__ LdsCoop lds;
    const int tid = threadIdx.x;
    const int blk = blockIdx.x;
    cg::grid_group grid = cg::this_grid();

    for (int t = blk * 256 + tid; t < 589824; t += 196608) cvt_x_one(t, x, xb);
    for (int t = blk * 256 + tid; t < 221184; t += 196608) cvt_w_one(t, w, wb);
    __threadfence();
    grid.sync();

    iter_phase_coop<true>(lds, xb, wb, outsum, s_part, tid, blk);
    __threadfence();
    grid.sync();
    if (blk < NBT * NO) squash_body<0>(lds.sq, s_part, outsum, nullptr, blk, tid);
    __threadfence();
    grid.sync();

    iter_phase_coop<false>(lds, xb, wb, outsum, s_part, tid, blk);
    __threadfence();
    grid.sync();
    if (blk < NBT * NO) squash_body<1>(lds.sq, s_part, outsum, nullptr, blk, tid);
    __threadfence();
    grid.sync();

    iter_phase_coop<false>(lds, xb, wb, outsum, s_part, tid, blk);
    __threadfence();
    grid.sync();
    if (blk < NBT * NO) squash_body<2>(lds.sq, s_part, nullptr, dout, blk, tid);
}

extern "C" void kernel_launch(void* const* d_in, const int* in_sizes, int n_in,
                              void* d_out, int out_size, void* d_ws, size_t ws_size,
                              hipStream_t stream) {
    const float* x = (const float*)d_in[0];   // [512][1152][8]
    const float* w = (const float*)d_in[1];   // [10][1152][16][8]
    float* out = (float*)d_out;               // [512][10][16]

    unsigned short* s_part = (unsigned short*)d_ws;
    float*          outsum = (float*)(s_part + SPART_H);
    unsigned short* xb     = (unsigned short*)(outsum + OUTSUM_F32);
    unsigned short* wb     = xb + XB_US;      // total ws ~= 17.2 MB

    void* args[] = { (void*)&x, (void*)&w, (void*)&xb, (void*)&wb,
                     (void*)&s_part, (void*)&outsum, (void*)&out };
    hipError_t e = hipLaunchCooperativeKernel(
        reinterpret_cast<void*>(caps_all), dim3(768), dim3(256), args, 0, stream);

    if (e != hipSuccess) {
        (void)hipGetLastError();   // clear sticky error; use fallback path
        cvt_xw<<<dim3(3168), dim3(256), 0, stream>>>(x, w, xb, wb);
        dim3 gI(NBT * NC), bI(256), gS(NBT * NO), bS(256);
        caps_iter<true ><<<gI, bI, 0, stream>>>(xb, wb, nullptr, s_part);
        caps_squash<0><<<gS, bS, 0, stream>>>(s_part, outsum, nullptr);
        caps_iter<false><<<gI, bI, 0, stream>>>(xb, wb, outsum, s_part);
        caps_squash<1><<<gS, bS, 0, stream>>>(s_part, outsum, nullptr);
        caps_iter<false><<<gI, bI, 0, stream>>>(xb, wb, outsum, s_part);
        caps_squash<2><<<gS, bS, 0, stream>>>(s_part, nullptr, out);
    }
}

// Round 13
// 320.135 us; speedup vs baseline: 2.8032x; 2.8032x over previous
//
#include <hip/hip_runtime.h>
#include <hip/hip_bf16.h>
#include <hip/hip_fp16.h>

#define B_    512
#define NI    1152
#define NO    10
#define BT    16
#define NBT   32           // B_/BT
#define NC    48           // chunks (8 XCD x 6)
#define NCH   24           // n per chunk
#define RNDS  3
#define RN    8            // n per staged round

#define WBUF_US 12288      // W round image: 24 granule-sets * 512 us
#define XBUF_US 1024       // x round image: 8 n * 128 us
#define BUF_US  13312      // W + x (26,624 B single buffer)

typedef __attribute__((ext_vector_type(8))) short bf16x8;
typedef __attribute__((ext_vector_type(4))) float f32x4;
typedef __attribute__((ext_vector_type(8))) unsigned short u16x8;

// workspace element counts
#define SPART_H    ((size_t)NC * NBT * NO * 256)      // 3,932,160 halfs (7.86 MB)
#define OUTSUM_F32 ((size_t)NBT * NO * 256)           //    81,920 f32  (0.33 MB)
#define XB_US      ((size_t)NBT * NC * RNDS * XBUF_US)// 4,718,592 us   (9.44 MB)
#define WB_US      ((size_t)NC * RNDS * WBUF_US)      // 1,769,472 us   (3.54 MB)

__device__ inline unsigned short f2bf(float f) {
    __hip_bfloat16 h = __float2bfloat16(f);
    return *reinterpret_cast<unsigned short*>(&h);
}

__device__ inline void gld_lds16(const void* g, void* lds) {
    __builtin_amdgcn_global_load_lds(
        (const __attribute__((address_space(1))) void*)g,
        (__attribute__((address_space(3))) void*)lds, 16, 0, 0);
}

// Fused conversion. Blocks [0,2304): x -> xb round images; [2304,3168): w -> wb.
// xb image per (bt,nc,r): 1024 us, [nl*128 + bl*8], nl in 0..7.
// wb image per (nc,r): 12288 us, [(nl*3+oq)*512 + (hi*16+d)*8], o = 4*oq+hi.
__global__ __launch_bounds__(256) void cvt_xw(
    const float* __restrict__ x, const float* __restrict__ w,
    unsigned short* __restrict__ xb, unsigned short* __restrict__ wb)
{
    const int blk = blockIdx.x;
    if (blk < 2304) {
        const int t   = blk * 256 + threadIdx.x;   // 589,824 granules
        const int m   = t & 127;
        const int img = t >> 7;                    // (bt*NC+nc)*3+r
        const int nl  = m >> 4, bl = m & 15;
        const int r   = img % RNDS;
        const int bc  = img / RNDS;
        const int nc  = bc % NC, bt = bc / NC;
        const int b   = bt * BT + bl;
        const int n   = nc * NCH + r * RN + nl;
        const float* src = x + ((size_t)b * NI + n) * 8;
        float4 v0 = *reinterpret_cast<const float4*>(src);
        float4 v1 = *reinterpret_cast<const float4*>(src + 4);
        u16x8 u = { f2bf(v0.x), f2bf(v0.y), f2bf(v0.z), f2bf(v0.w),
                    f2bf(v1.x), f2bf(v1.y), f2bf(v1.z), f2bf(v1.w) };
        *reinterpret_cast<u16x8*>(xb + (size_t)t * 8) = u;
    } else {
        const int t    = (blk - 2304) * 256 + threadIdx.x;  // 221,184 granules
        const int lane = t & 63;
        const int gs   = (t >> 6) % 24;
        const int img  = t / 1536;                 // nc*3+r
        const int hi   = lane >> 4, d = lane & 15;
        const int nl   = gs / 3, oq = gs % 3;
        const int r    = img % RNDS, nc = img / RNDS;
        const int o    = oq * 4 + hi;
        const int n    = nc * NCH + r * RN + nl;
        u16x8 u = {0,0,0,0,0,0,0,0};
        if (o < NO) {
            const float* src = w + ((size_t)o * NI + n) * 128 + d * 8;
            float4 v0 = *reinterpret_cast<const float4*>(src);
            float4 v1 = *reinterpret_cast<const float4*>(src + 4);
            u = (u16x8){ f2bf(v0.x), f2bf(v0.y), f2bf(v0.z), f2bf(v0.w),
                         f2bf(v1.x), f2bf(v1.y), f2bf(v1.z), f2bf(v1.w) };
        }
        *reinterpret_cast<u16x8*>(wb + (size_t)t * 8) = u;
    }
}

union LdsU {
    unsigned short stage[BUF_US];       // 26,624 B (single buffer -> 6 blk/CU)
    uint2 red[4][NO * 64];              // 20,480 B (fp16-packed epilogue)
};

// One routing iteration. Block = bt x nc (grid 1536 = 6 blocks/CU, 24
// waves/CU). 3 single-buffered rounds of 8 n (2 per wave); round-10
// compute core verbatim. Cross-block TLP hides stage drains.
template<bool UNIFORM>
__global__ __launch_bounds__(256, 6) void caps_iter(
    const unsigned short* __restrict__ xb,
    const unsigned short* __restrict__ wb,
    const float* __restrict__ outsum,    // [bt*10+o][64][4] lane-major f32
    unsigned short* __restrict__ s_part) // [nc][bt][o][64][4] fp16
{
    __shared__ LdsU lds;

    const int tid = threadIdx.x;
    const int w   = tid >> 6;
    const int l   = tid & 63;
    const int b16 = l & 15;
    const int hi  = l >> 4;
    const int blk = blockIdx.x;
    const int xcd = blk & 7, idx = blk >> 3;     // XCD owns 6 chunks
    const int nc  = xcd * 6 + (idx >> 5);
    const int bt  = idx & 31;

    const unsigned short* wsrc = wb + (size_t)nc * (RNDS * WBUF_US);
    const unsigned short* xsrc = xb + ((size_t)bt * NC + nc) * (RNDS * XBUF_US);

    f32x4 outf[NO];
    if constexpr (!UNIFORM) {
        #pragma unroll
        for (int o = 0; o < NO; ++o)
            outf[o] = *reinterpret_cast<const f32x4*>(
                outsum + (((size_t)bt * NO + o) * 64 + l) * 4);
    }

    f32x4 sacc[NO];
    #pragma unroll
    for (int o = 0; o < NO; ++o) sacc[o] = (f32x4){0.f, 0.f, 0.f, 0.f};

    #pragma unroll 1
    for (int r = 0; r < RNDS; ++r) {
        // stage this round (single buffer)
        const unsigned short* wr = wsrc + (size_t)r * WBUF_US;
        #pragma unroll
        for (int k = 0; k < 6; ++k)          // 1536 16B chunks of W
            gld_lds16(wr + (k * 256 + tid) * 8,
                      (char*)lds.stage + (k * 256 + tid) * 16);
        if (tid < 128)                       // 128 16B chunks of x
            gld_lds16(xsrc + (size_t)r * XBUF_US + tid * 8,
                      (char*)lds.stage + WBUF_US * 2 + tid * 16);
        asm volatile("s_waitcnt vmcnt(0)" ::: "memory");
        __syncthreads();

        #pragma unroll 1
        for (int i = 0; i < 2; ++i) {
            const int nl = w * 2 + i;                  // wave's n within round
            bf16x8 bv = *reinterpret_cast<const bf16x8*>(
                &lds.stage[WBUF_US + nl * 128 + b16 * 8]);
            bf16x8 bvt[4];
            #pragma unroll
            for (int t = 0; t < 4; ++t)
                bvt[t] = (hi == t) ? bv : (bf16x8){0,0,0,0,0,0,0,0};

            if constexpr (UNIFORM) {
                #pragma unroll
                for (int oq = 0; oq < 3; ++oq) {
                    bf16x8 av = *reinterpret_cast<const bf16x8*>(
                        &lds.stage[(nl * 3 + oq) * 512 + l * 8]);
                    const int tmax = (oq < 2) ? 4 : 2;
                    #pragma unroll
                    for (int t = 0; t < tmax; ++t)
                        sacc[oq * 4 + t] = __builtin_amdgcn_mfma_f32_16x16x32_bf16(
                            av, bvt[t], sacc[oq * 4 + t], 0, 0, 0);
                }
            } else {
                f32x4 xh[NO];
                float lg[NO];
                #pragma unroll
                for (int oq = 0; oq < 3; ++oq) {
                    bf16x8 av = *reinterpret_cast<const bf16x8*>(
                        &lds.stage[(nl * 3 + oq) * 512 + l * 8]);
                    const int tmax = (oq < 2) ? 4 : 2;
                    #pragma unroll
                    for (int t = 0; t < tmax; ++t) {
                        const int o = oq * 4 + t;
                        xh[o] = __builtin_amdgcn_mfma_f32_16x16x32_bf16(
                            av, bvt[t], (f32x4){0.f, 0.f, 0.f, 0.f}, 0, 0, 0);
                        float pp = outf[o][0] * xh[o][0];
                        pp = fmaf(outf[o][1], xh[o][1], pp);
                        pp = fmaf(outf[o][2], xh[o][2], pp);
                        pp = fmaf(outf[o][3], xh[o][3], pp);
                        pp += __shfl_xor(pp, 16, 64);
                        pp += __shfl_xor(pp, 32, 64);
                        lg[o] = pp;
                    }
                }
                float sum = 0.f;
                #pragma unroll
                for (int o = 0; o < NO; ++o) { lg[o] = __expf(lg[o]); sum += lg[o]; }
                const float rs = __builtin_amdgcn_rcpf(sum);
                #pragma unroll
                for (int o = 0; o < NO; ++o) {
                    const float cc = lg[o] * rs;
                    sacc[o][0] = fmaf(cc, xh[o][0], sacc[o][0]);
                    sacc[o][1] = fmaf(cc, xh[o][1], sacc[o][1]);
                    sacc[o][2] = fmaf(cc, xh[o][2], sacc[o][2]);
                    sacc[o][3] = fmaf(cc, xh[o][3], sacc[o][3]);
                }
            }
        }
        __syncthreads();   // all reads done before next round overwrites
    }

    // cross-wave reduce, fp16-packed, lane-consecutive = conflict-free
    const float sc = UNIFORM ? 0.1f : 1.0f;
    #pragma unroll
    for (int o = 0; o < NO; ++o) {
        __half2 h01 = __floats2half2_rn(sacc[o][0] * sc, sacc[o][1] * sc);
        __half2 h23 = __floats2half2_rn(sacc[o][2] * sc, sacc[o][3] * sc);
        lds.red[w][o * 64 + l] =
            make_uint2(*reinterpret_cast<unsigned int*>(&h01),
                       *reinterpret_cast<unsigned int*>(&h23));
    }
    __syncthreads();
    unsigned short* base = s_part + ((size_t)nc * NBT + bt) * 2560;
    for (int g = tid; g < NO * 64; g += 256) {
        uint2 a0 = lds.red[0][g], a1 = lds.red[1][g],
              a2 = lds.red[2][g], a3 = lds.red[3][g];
        auto h2f2 = [](unsigned int u) {
            __half2 h = *reinterpret_cast<__half2*>(&u);
            return __half22float2(h);
        };
        float2 lo = h2f2(a0.x), l1 = h2f2(a1.x), l2 = h2f2(a2.x), l3 = h2f2(a3.x);
        float2 ho = h2f2(a0.y), h1 = h2f2(a1.y), h2 = h2f2(a2.y), h3 = h2f2(a3.y);
        float2 sl = { (lo.x + l1.x) + (l2.x + l3.x), (lo.y + l1.y) + (l2.y + l3.y) };
        float2 sh = { (ho.x + h1.x) + (h2.x + h3.x), (ho.y + h1.y) + (h2.y + h3.y) };
        __half2 p01 = __floats2half2_rn(sl.x, sl.y);
        __half2 p23 = __floats2half2_rn(sh.x, sh.y);
        *reinterpret_cast<uint2*>(base + (size_t)g * 4) =
            make_uint2(*reinterpret_cast<unsigned int*>(&p01),
                       *reinterpret_cast<unsigned int*>(&p23));
    }
}

// Reduce chunks + squash. Block bo = bt*10+o; thread t: l=t>>2, q=t&3.
template<int MODE>
__global__ __launch_bounds__(256) void caps_squash(
    const unsigned short* __restrict__ s_part,
    float* __restrict__ outsum,
    float* __restrict__ dout)
{
    __shared__ float sq[256];
    const int bo = blockIdx.x;
    const int t  = threadIdx.x;

    float s = 0.f;
    #pragma unroll 4
    for (int nc = 0; nc < NC; ++nc) {
        __half h = *reinterpret_cast<const __half*>(
            s_part + ((size_t)nc * NBT * NO + bo) * 256 + t);
        s += __half2float(h);
    }

    float n2 = s * s;
    n2 += __shfl_xor(n2, 1, 64);
    n2 += __shfl_xor(n2, 2, 64);       // q-pair reduced
    sq[t] = n2;
    __syncthreads();
    const int base = t & 63;
    n2 = (sq[base] + sq[64 + base]) + (sq[128 + base] + sq[192 + base]);

    const float norm  = sqrtf(n2);
    const float scale = n2 / ((1.f + n2) * (norm + 1e-8f));
    const float v = scale * s;

    if constexpr (MODE == 0) {
        outsum[(size_t)bo * 256 + t] = v;
    } else if constexpr (MODE == 1) {
        outsum[(size_t)bo * 256 + t] += v;
    } else {
        const int bt = bo / NO, o = bo - bt * NO;
        const int b16 = (t >> 2) & 15, hi = t >> 6, q = t & 3;
        dout[((size_t)(bt * BT + b16) * NO + o) * 16 + hi * 4 + q] = v;
    }
}

extern "C" void kernel_launch(void* const* d_in, const int* in_sizes, int n_in,
                              void* d_out, int out_size, void* d_ws, size_t ws_size,
                              hipStream_t stream) {
    const float* x = (const float*)d_in[0];   // [512][1152][8]
    const float* w = (const float*)d_in[1];   // [10][1152][16][8]
    float* out = (float*)d_out;               // [512][10][16]

    unsigned short* s_part = (unsigned short*)d_ws;
    float*          outsum = (float*)(s_part + SPART_H);
    unsigned short* xb     = (unsigned short*)(outsum + OUTSUM_F32);
    unsigned short* wb     = xb + XB_US;      // total ws ~= 21.2 MB

    cvt_xw<<<dim3(3168), dim3(256), 0, stream>>>(x, w, xb, wb);

    dim3 gI(NBT * NC), bI(256);               // 1536 blocks = 6/CU
    dim3 gS(NBT * NO), bS(256);               // 320 blocks

    caps_iter<true ><<<gI, bI, 0, stream>>>(xb, wb, nullptr, s_part);
    caps_squash<0><<<gS, bS, 0, stream>>>(s_part, outsum, nullptr);
    caps_iter<false><<<gI, bI, 0, stream>>>(xb, wb, outsum, s_part);
    caps_squash<1><<<gS, bS, 0, stream>>>(s_part, outsum, nullptr);
    caps_iter<false><<<gI, bI, 0, stream>>>(xb, wb, outsum, s_part);
    caps_squash<2><<<gS, bS, 0, stream>>>(s_part, nullptr, out);
}

// Round 14
// 203.318 us; speedup vs baseline: 4.4138x; 1.5746x over previous
//
#include <hip/hip_runtime.h>
#include <hip/hip_bf16.h>
#include <hip/hip_fp16.h>

#define B_    512
#define NI    1152
#define NO    10
#define BT    16
#define NBT   32           // B_/BT
#define NC    48           // chunks (8 XCD x 6)
#define NCH   24           // n per chunk
#define RNDS  3
#define RN    8            // n per staged round

#define WBUF_US 12288      // W round image: 24 granule-sets * 512 us
#define XBUF_US 1024       // x round image: 8 n * 128 us
#define BUF_US  13312      // W + x (26,624 B single buffer)

typedef __attribute__((ext_vector_type(8))) short bf16x8;
typedef __attribute__((ext_vector_type(4))) float f32x4;
typedef __attribute__((ext_vector_type(8))) unsigned short u16x8;

// workspace element counts
#define SPART_H    ((size_t)NC * NBT * NO * 256)      // 3,932,160 halfs (7.86 MB)
#define OUTSUM_F32 ((size_t)NBT * NO * 256)           //    81,920 f32  (0.33 MB)
#define XB_US      ((size_t)NBT * NC * RNDS * XBUF_US)// 4,718,592 us   (9.44 MB)
#define WB_US      ((size_t)NC * RNDS * WBUF_US)      // 1,769,472 us   (3.54 MB)

__device__ inline unsigned short f2bf(float f) {
    __hip_bfloat16 h = __float2bfloat16(f);
    return *reinterpret_cast<unsigned short*>(&h);
}

__device__ inline void gld_lds16(const void* g, void* lds) {
    __builtin_amdgcn_global_load_lds(
        (const __attribute__((address_space(1))) void*)g,
        (__attribute__((address_space(3))) void*)lds, 16, 0, 0);
}

// Fused conversion. Blocks [0,2304): x -> xb round images; [2304,3168): w -> wb.
// xb image per (bt,nc,r): 1024 us, [nl*128 + bl*8], nl in 0..7.
// wb image per (nc,r): 12288 us, [(nl*3+oq)*512 + (hi*16+d)*8], o = 4*oq+hi.
__global__ __launch_bounds__(256) void cvt_xw(
    const float* __restrict__ x, const float* __restrict__ w,
    unsigned short* __restrict__ xb, unsigned short* __restrict__ wb)
{
    const int blk = blockIdx.x;
    if (blk < 2304) {
        const int t   = blk * 256 + threadIdx.x;   // 589,824 granules
        const int m   = t & 127;
        const int img = t >> 7;                    // (bt*NC+nc)*3+r
        const int nl  = m >> 4, bl = m & 15;
        const int r   = img % RNDS;
        const int bc  = img / RNDS;
        const int nc  = bc % NC, bt = bc / NC;
        const int b   = bt * BT + bl;
        const int n   = nc * NCH + r * RN + nl;
        const float* src = x + ((size_t)b * NI + n) * 8;
        float4 v0 = *reinterpret_cast<const float4*>(src);
        float4 v1 = *reinterpret_cast<const float4*>(src + 4);
        u16x8 u = { f2bf(v0.x), f2bf(v0.y), f2bf(v0.z), f2bf(v0.w),
                    f2bf(v1.x), f2bf(v1.y), f2bf(v1.z), f2bf(v1.w) };
        *reinterpret_cast<u16x8*>(xb + (size_t)t * 8) = u;
    } else {
        const int t    = (blk - 2304) * 256 + threadIdx.x;  // 221,184 granules
        const int lane = t & 63;
        const int gs   = (t >> 6) % 24;
        const int img  = t / 1536;                 // nc*3+r
        const int hi   = lane >> 4, d = lane & 15;
        const int nl   = gs / 3, oq = gs % 3;
        const int r    = img % RNDS, nc = img / RNDS;
        const int o    = oq * 4 + hi;
        const int n    = nc * NCH + r * RN + nl;
        u16x8 u = {0,0,0,0,0,0,0,0};
        if (o < NO) {
            const float* src = w + ((size_t)o * NI + n) * 128 + d * 8;
            float4 v0 = *reinterpret_cast<const float4*>(src);
            float4 v1 = *reinterpret_cast<const float4*>(src + 4);
            u = (u16x8){ f2bf(v0.x), f2bf(v0.y), f2bf(v0.z), f2bf(v0.w),
                         f2bf(v1.x), f2bf(v1.y), f2bf(v1.z), f2bf(v1.w) };
        }
        *reinterpret_cast<u16x8*>(wb + (size_t)t * 8) = u;
    }
}

union LdsU {
    unsigned short stage[BUF_US];       // 26,624 B (single buffer -> 6 blk/CU)
    uint2 red[4][NO * 64];              // 20,480 B (fp16-packed epilogue)
};

// One routing iteration. Block = bt x nc (grid 1536). LDS 26,624 B and
// VGPR ~84 both allow 6 blocks/CU; launch_bounds(256,4) keeps the VGPR cap
// at 128 so the 84-reg live set does NOT spill (the round-13 bug was (256,6)
// -> 40 VGPRs -> scratch thrash). Cross-block TLP hides the per-round
// stage drain, so single-buffering suffices.
template<bool UNIFORM>
__global__ __launch_bounds__(256, 4) void caps_iter(
    const unsigned short* __restrict__ xb,
    const unsigned short* __restrict__ wb,
    const float* __restrict__ outsum,    // [bt*10+o][64][4] lane-major f32
    unsigned short* __restrict__ s_part) // [nc][bt][o][64][4] fp16
{
    __shared__ LdsU lds;

    const int tid = threadIdx.x;
    const int w   = tid >> 6;
    const int l   = tid & 63;
    const int b16 = l & 15;
    const int hi  = l >> 4;
    const int blk = blockIdx.x;
    const int xcd = blk & 7, idx = blk >> 3;     // XCD owns 6 chunks
    const int nc  = xcd * 6 + (idx >> 5);
    const int bt  = idx & 31;

    const unsigned short* wsrc = wb + (size_t)nc * (RNDS * WBUF_US);
    const unsigned short* xsrc = xb + ((size_t)bt * NC + nc) * (RNDS * XBUF_US);

    f32x4 outf[NO];
    if constexpr (!UNIFORM) {
        #pragma unroll
        for (int o = 0; o < NO; ++o)
            outf[o] = *reinterpret_cast<const f32x4*>(
                outsum + (((size_t)bt * NO + o) * 64 + l) * 4);
    }

    f32x4 sacc[NO];
    #pragma unroll
    for (int o = 0; o < NO; ++o) sacc[o] = (f32x4){0.f, 0.f, 0.f, 0.f};

    #pragma unroll 1
    for (int r = 0; r < RNDS; ++r) {
        // stage this round (single buffer)
        const unsigned short* wr = wsrc + (size_t)r * WBUF_US;
        #pragma unroll
        for (int k = 0; k < 6; ++k)          // 1536 16B chunks of W
            gld_lds16(wr + (k * 256 + tid) * 8,
                      (char*)lds.stage + (k * 256 + tid) * 16);
        if (tid < 128)                       // 128 16B chunks of x
            gld_lds16(xsrc + (size_t)r * XBUF_US + tid * 8,
                      (char*)lds.stage + WBUF_US * 2 + tid * 16);
        asm volatile("s_waitcnt vmcnt(0)" ::: "memory");
        __syncthreads();

        #pragma unroll 1
        for (int i = 0; i < 2; ++i) {
            const int nl = w * 2 + i;                  // wave's n within round
            bf16x8 bv = *reinterpret_cast<const bf16x8*>(
                &lds.stage[WBUF_US + nl * 128 + b16 * 8]);
            bf16x8 bvt[4];
            #pragma unroll
            for (int t = 0; t < 4; ++t)
                bvt[t] = (hi == t) ? bv : (bf16x8){0,0,0,0,0,0,0,0};

            if constexpr (UNIFORM) {
                #pragma unroll
                for (int oq = 0; oq < 3; ++oq) {
                    bf16x8 av = *reinterpret_cast<const bf16x8*>(
                        &lds.stage[(nl * 3 + oq) * 512 + l * 8]);
                    const int tmax = (oq < 2) ? 4 : 2;
                    #pragma unroll
                    for (int t = 0; t < tmax; ++t)
                        sacc[oq * 4 + t] = __builtin_amdgcn_mfma_f32_16x16x32_bf16(
                            av, bvt[t], sacc[oq * 4 + t], 0, 0, 0);
                }
            } else {
                f32x4 xh[NO];
                float lg[NO];
                #pragma unroll
                for (int oq = 0; oq < 3; ++oq) {
                    bf16x8 av = *reinterpret_cast<const bf16x8*>(
                        &lds.stage[(nl * 3 + oq) * 512 + l * 8]);
                    const int tmax = (oq < 2) ? 4 : 2;
                    #pragma unroll
                    for (int t = 0; t < tmax; ++t) {
                        const int o = oq * 4 + t;
                        xh[o] = __builtin_amdgcn_mfma_f32_16x16x32_bf16(
                            av, bvt[t], (f32x4){0.f, 0.f, 0.f, 0.f}, 0, 0, 0);
                        float pp = outf[o][0] * xh[o][0];
                        pp = fmaf(outf[o][1], xh[o][1], pp);
                        pp = fmaf(outf[o][2], xh[o][2], pp);
                        pp = fmaf(outf[o][3], xh[o][3], pp);
                        pp += __shfl_xor(pp, 16, 64);
                        pp += __shfl_xor(pp, 32, 64);
                        lg[o] = pp;
                    }
                }
                float sum = 0.f;
                #pragma unroll
                for (int o = 0; o < NO; ++o) { lg[o] = __expf(lg[o]); sum += lg[o]; }
                const float rs = __builtin_amdgcn_rcpf(sum);
                #pragma unroll
                for (int o = 0; o < NO; ++o) {
                    const float cc = lg[o] * rs;
                    sacc[o][0] = fmaf(cc, xh[o][0], sacc[o][0]);
                    sacc[o][1] = fmaf(cc, xh[o][1], sacc[o][1]);
                    sacc[o][2] = fmaf(cc, xh[o][2], sacc[o][2]);
                    sacc[o][3] = fmaf(cc, xh[o][3], sacc[o][3]);
                }
            }
        }
        __syncthreads();   // all reads done before next round overwrites
    }

    // cross-wave reduce, fp16-packed, lane-consecutive = conflict-free
    const float sc = UNIFORM ? 0.1f : 1.0f;
    #pragma unroll
    for (int o = 0; o < NO; ++o) {
        __half2 h01 = __floats2half2_rn(sacc[o][0] * sc, sacc[o][1] * sc);
        __half2 h23 = __floats2half2_rn(sacc[o][2] * sc, sacc[o][3] * sc);
        lds.red[w][o * 64 + l] =
            make_uint2(*reinterpret_cast<unsigned int*>(&h01),
                       *reinterpret_cast<unsigned int*>(&h23));
    }
    __syncthreads();
    unsigned short* base = s_part + ((size_t)nc * NBT + bt) * 2560;
    for (int g = tid; g < NO * 64; g += 256) {
        uint2 a0 = lds.red[0][g], a1 = lds.red[1][g],
              a2 = lds.red[2][g], a3 = lds.red[3][g];
        auto h2f2 = [](unsigned int u) {
            __half2 h = *reinterpret_cast<__half2*>(&u);
            return __half22float2(h);
        };
        float2 lo = h2f2(a0.x), l1 = h2f2(a1.x), l2 = h2f2(a2.x), l3 = h2f2(a3.x);
        float2 ho = h2f2(a0.y), h1 = h2f2(a1.y), h2 = h2f2(a2.y), h3 = h2f2(a3.y);
        float2 sl = { (lo.x + l1.x) + (l2.x + l3.x), (lo.y + l1.y) + (l2.y + l3.y) };
        float2 sh = { (ho.x + h1.x) + (h2.x + h3.x), (ho.y + h1.y) + (h2.y + h3.y) };
        __half2 p01 = __floats2half2_rn(sl.x, sl.y);
        __half2 p23 = __floats2half2_rn(sh.x, sh.y);
        *reinterpret_cast<uint2*>(base + (size_t)g * 4) =
            make_uint2(*reinterpret_cast<unsigned int*>(&p01),
                       *reinterpret_cast<unsigned int*>(&p23));
    }
}

// Reduce chunks + squash. Block bo = bt*10+o; thread t: l=t>>2, q=t&3.
template<int MODE>
__global__ __launch_bounds__(256) void caps_squash(
    const unsigned short* __restrict__ s_part,
    float* __restrict__ outsum,
    float* __restrict__ dout)
{
    __shared__ float sq[256];
    const int bo = blockIdx.x;
    const int t  = threadIdx.x;

    float s = 0.f;
    #pragma unroll 4
    for (int nc = 0; nc < NC; ++nc) {
        __half h = *reinterpret_cast<const __half*>(
            s_part + ((size_t)nc * NBT * NO + bo) * 256 + t);
        s += __half2float(h);
    }

    float n2 = s * s;
    n2 += __shfl_xor(n2, 1, 64);
    n2 += __shfl_xor(n2, 2, 64);       // q-pair reduced
    sq[t] = n2;
    __syncthreads();
    const int base = t & 63;
    n2 = (sq[base] + sq[64 + base]) + (sq[128 + base] + sq[192 + base]);

    const float norm  = sqrtf(n2);
    const float scale = n2 / ((1.f + n2) * (norm + 1e-8f));
    const float v = scale * s;

    if constexpr (MODE == 0) {
        outsum[(size_t)bo * 256 + t] = v;
    } else if constexpr (MODE == 1) {
        outsum[(size_t)bo * 256 + t] += v;
    } else {
        const int bt = bo / NO, o = bo - bt * NO;
        const int b16 = (t >> 2) & 15, hi = t >> 6, q = t & 3;
        dout[((size_t)(bt * BT + b16) * NO + o) * 16 + hi * 4 + q] = v;
    }
}

extern "C" void kernel_launch(void* const* d_in, const int* in_sizes, int n_in,
                              void* d_out, int out_size, void* d_ws, size_t ws_size,
                              hipStream_t stream) {
    const float* x = (const float*)d_in[0];   // [512][1152][8]
    const float* w = (const float*)d_in[1];   // [10][1152][16][8]
    float* out = (float*)d_out;               // [512][10][16]

    unsigned short* s_part = (unsigned short*)d_ws;
    float*          outsum = (float*)(s_part + SPART_H);
    unsigned short* xb     = (unsigned short*)(outsum + OUTSUM_F32);
    unsigned short* wb     = xb + XB_US;      // total ws ~= 21.2 MB

    cvt_xw<<<dim3(3168), dim3(256), 0, stream>>>(x, w, xb, wb);

    dim3 gI(NBT * NC), bI(256);               // 1536 blocks = 6/CU
    dim3 gS(NBT * NO), bS(256);               // 320 blocks

    caps_iter<true ><<<gI, bI, 0, stream>>>(xb, wb, nullptr, s_part);
    caps_squash<0><<<gS, bS, 0, stream>>>(s_part, outsum, nullptr);
    caps_iter<false><<<gI, bI, 0, stream>>>(xb, wb, outsum, s_part);
    caps_squash<1><<<gS, bS, 0, stream>>>(s_part, outsum, nullptr);
    caps_iter<false><<<gI, bI, 0, stream>>>(xb, wb, outsum, s_part);
    caps_squash<2><<<gS, bS, 0, stream>>>(s_part, nullptr, out);
}

// Round 15
// 68.269 us; speedup vs baseline: 13.1453x; 2.9782x over previous
//
#include <hip/hip_runtime.h>
#include <hip/hip_bf16.h>
#include <hip/hip_fp16.h>

#define B_    512
#define NI    1152
#define NO    10
#define BT    16
#define NBT   32           // B_/BT
#define NC    24           // chunks (8 XCD x 3)
#define NCH   48           // n per chunk
#define RNDS  6
#define RN    8            // n per image round

typedef __attribute__((ext_vector_type(8))) short bf16x8;
typedef __attribute__((ext_vector_type(4))) float f32x4;
typedef __attribute__((ext_vector_type(8))) unsigned short u16x8;

// workspace element counts (identical layout to round 10)
#define SPART_H    ((size_t)NC * NBT * NO * 256)      // 1,966,080 halfs (3.93 MB)
#define OUTSUM_F32 ((size_t)NBT * NO * 256)           //    81,920 f32  (0.33 MB)
#define XB_US      ((size_t)NBT * NC * RNDS * 1024)   // 4,718,592 us   (9.44 MB)
#define WB_US      ((size_t)NC * RNDS * 12288)        // 1,769,472 us   (3.54 MB)

__device__ inline unsigned short f2bf(float f) {
    __hip_bfloat16 h = __float2bfloat16(f);
    return *reinterpret_cast<unsigned short*>(&h);
}

__device__ __forceinline__ bf16x8 load_cvt8(const float* src) {
    f32x4 v0 = *reinterpret_cast<const f32x4*>(src);
    f32x4 v1 = *reinterpret_cast<const f32x4*>(src + 4);
    u16x8 u = { f2bf(v0[0]), f2bf(v0[1]), f2bf(v0[2]), f2bf(v0[3]),
                f2bf(v1[0]), f2bf(v1[1]), f2bf(v1[2]), f2bf(v1[3]) };
    return *reinterpret_cast<bf16x8*>(&u);
}

// fp16-packed cross-wave reduce + coalesced s_part store (round-10 epilogue)
__device__ __forceinline__ void iter_epilogue(
    uint2 (*red)[NO * 64], const f32x4* sacc, float sc,
    int w, int l, int tid, unsigned short* base)
{
    #pragma unroll
    for (int o = 0; o < NO; ++o) {
        __half2 h01 = __floats2half2_rn(sacc[o][0] * sc, sacc[o][1] * sc);
        __half2 h23 = __floats2half2_rn(sacc[o][2] * sc, sacc[o][3] * sc);
        red[w][o * 64 + l] =
            make_uint2(*reinterpret_cast<unsigned int*>(&h01),
                       *reinterpret_cast<unsigned int*>(&h23));
    }
    __syncthreads();
    for (int g = tid; g < NO * 64; g += 256) {
        uint2 a0 = red[0][g], a1 = red[1][g], a2 = red[2][g], a3 = red[3][g];
        auto h2f2 = [](unsigned int u) {
            __half2 h = *reinterpret_cast<__half2*>(&u);
            return __half22float2(h);
        };
        float2 lo = h2f2(a0.x), l1 = h2f2(a1.x), l2 = h2f2(a2.x), l3 = h2f2(a3.x);
        float2 ho = h2f2(a0.y), h1 = h2f2(a1.y), h2 = h2f2(a2.y), h3 = h2f2(a3.y);
        float2 sl = { (lo.x + l1.x) + (l2.x + l3.x), (lo.y + l1.y) + (l2.y + l3.y) };
        float2 sh = { (ho.x + h1.x) + (h2.x + h3.x), (ho.y + h1.y) + (h2.y + h3.y) };
        __half2 p01 = __floats2half2_rn(sl.x, sl.y);
        __half2 p23 = __floats2half2_rn(sh.x, sh.y);
        *reinterpret_cast<uint2*>(base + (size_t)g * 4) =
            make_uint2(*reinterpret_cast<unsigned int*>(&p01),
                       *reinterpret_cast<unsigned int*>(&p23));
    }
}

// ---- kernel 1: fused cvt (x,W -> bf16 images) + uniform iter0 -----------
// Block (bt,nc). (a) writes its xb slice; (b) writes a 288-granule share of
// wb; (c) computes iter0 (c=0.1) with 4n-packed UNMASKED MFMA straight from
// f32 (no LDS, no barriers in compute).
__global__ __launch_bounds__(256) void caps_f0(
    const float* __restrict__ x, const float* __restrict__ w,
    unsigned short* __restrict__ xb, unsigned short* __restrict__ wb,
    unsigned short* __restrict__ s_part)
{
    __shared__ uint2 red[4][NO * 64];   // 20,480 B (epilogue only)

    const int tid = threadIdx.x;
    const int wv  = tid >> 6;
    const int l   = tid & 63;
    const int b16 = l & 15;
    const int hi  = l >> 4;
    const int blk = blockIdx.x;
    const int xcd = blk & 7, idx = blk >> 3;
    const int nc  = xcd * 3 + (idx >> 5);
    const int bt  = idx & 31;

    // (a) x -> xb slice for this (bt,nc): 768 granules (round-10 cvt math)
    #pragma unroll
    for (int k = 0; k < 3; ++k) {
        const int gid = k * 256 + tid;
        const int r   = gid >> 7, m = gid & 127;
        const int nl  = m >> 4, bl = m & 15;
        const int b   = bt * BT + bl;
        const int n   = nc * NCH + r * RN + nl;
        const size_t img = (size_t)(bt * NC + nc) * RNDS + r;
        bf16x8 u = load_cvt8(x + ((size_t)b * NI + n) * 8);
        *reinterpret_cast<bf16x8*>(xb + (img * 128 + m) * 8) = u;
    }

    // (b) w -> wb share: granules [blk*288, blk*288+288)
    #pragma unroll
    for (int k = 0; k < 2; ++k) {
        const int loc = k * 256 + tid;
        if (loc < 288) {
            const int t    = blk * 288 + loc;
            const int lane = t & 63;
            const int gs   = (t >> 6) % 24;
            const int img  = t / 1536;               // ncw*6+r
            const int h2   = lane >> 4, d = lane & 15;
            const int nl   = gs / 3, oq = gs % 3;
            const int r    = img % RNDS, ncw = img / RNDS;
            const int o    = oq * 4 + h2;
            const int n    = ncw * NCH + r * RN + nl;
            bf16x8 u = (bf16x8){0,0,0,0,0,0,0,0};
            if (o < NO)
                u = load_cvt8(w + ((size_t)o * NI + n) * 128 + d * 8);
            *reinterpret_cast<bf16x8*>(wb + (size_t)t * 8) = u;
        }
    }

    // (c) uniform iter0: wave wv covers n-local wv*12 .. +11 in 3 packed groups
    f32x4 sacc[NO];
    #pragma unroll
    for (int o = 0; o < NO; ++o) sacc[o] = (f32x4){0.f, 0.f, 0.f, 0.f};

    const int bg = bt * BT + b16;
    #pragma unroll 1
    for (int g = 0; g < 3; ++g) {
        const int n_lane = nc * NCH + wv * 12 + g * 4 + hi;  // packed k-block hi
        bf16x8 bv4 = load_cvt8(x + ((size_t)bg * NI + n_lane) * 8);
        #pragma unroll
        for (int o = 0; o < NO; ++o) {
            bf16x8 av4 = load_cvt8(w + ((size_t)o * NI + n_lane) * 128 + b16 * 8);
            sacc[o] = __builtin_amdgcn_mfma_f32_16x16x32_bf16(
                av4, bv4, sacc[o], 0, 0, 0);   // sums 4 n per MFMA
        }
    }

    iter_epilogue(red, sacc, 0.1f, wv, l, tid,
                  s_part + ((size_t)nc * NBT + bt) * 2560);
}

// ---- kernels 2,3: routing iteration, NO LDS staging ---------------------
// av/bv MFMA fragments load directly from the bf16 images (coalesced,
// L2-resident). No barriers until the epilogue. Round-10 compute core.
__global__ __launch_bounds__(256, 3) void caps_itr(
    const unsigned short* __restrict__ xb,
    const unsigned short* __restrict__ wb,
    const float* __restrict__ outsum,    // [bt*10+o][64][4] lane-major f32
    unsigned short* __restrict__ s_part) // [nc][bt][o][64][4] fp16
{
    __shared__ uint2 red[4][NO * 64];   // 20,480 B (epilogue only)

    const int tid = threadIdx.x;
    const int wv  = tid >> 6;
    const int l   = tid & 63;
    const int b16 = l & 15;
    const int hi  = l >> 4;
    const int blk = blockIdx.x;
    const int xcd = blk & 7, idx = blk >> 3;
    const int nc  = xcd * 3 + (idx >> 5);
    const int bt  = idx & 31;

    f32x4 outf[NO];
    #pragma unroll
    for (int o = 0; o < NO; ++o)
        outf[o] = *reinterpret_cast<const f32x4*>(
            outsum + (((size_t)bt * NO + o) * 64 + l) * 4);

    f32x4 sacc[NO];
    #pragma unroll
    for (int o = 0; o < NO; ++o) sacc[o] = (f32x4){0.f, 0.f, 0.f, 0.f};

    const unsigned short* xbase = xb + (size_t)(bt * NC + nc) * (RNDS * 1024);
    const unsigned short* wbase = wb + (size_t)nc * (RNDS * 12288);

    #pragma unroll 1
    for (int r = 0; r < RNDS; ++r) {
        const unsigned short* xr = xbase + (size_t)r * 1024;
        const unsigned short* wr = wbase + (size_t)r * 12288;
        #pragma unroll 1
        for (int i = 0; i < 2; ++i) {
            const int nl = wv * 2 + i;
            bf16x8 bv = *reinterpret_cast<const bf16x8*>(
                xr + nl * 128 + b16 * 8);
            bf16x8 avv[3];
            #pragma unroll
            for (int oq = 0; oq < 3; ++oq)
                avv[oq] = *reinterpret_cast<const bf16x8*>(
                    wr + (nl * 3 + oq) * 512 + l * 8);
            bf16x8 bvt[4];
            #pragma unroll
            for (int t = 0; t < 4; ++t)
                bvt[t] = (hi == t) ? bv : (bf16x8){0,0,0,0,0,0,0,0};

            f32x4 xh[NO];
            float lg[NO];
            #pragma unroll
            for (int oq = 0; oq < 3; ++oq) {
                const int tmax = (oq < 2) ? 4 : 2;
                #pragma unroll
                for (int t = 0; t < tmax; ++t) {
                    const int o = oq * 4 + t;
                    xh[o] = __builtin_amdgcn_mfma_f32_16x16x32_bf16(
                        avv[oq], bvt[t], (f32x4){0.f, 0.f, 0.f, 0.f}, 0, 0, 0);
                    float pp = outf[o][0] * xh[o][0];
                    pp = fmaf(outf[o][1], xh[o][1], pp);
                    pp = fmaf(outf[o][2], xh[o][2], pp);
                    pp = fmaf(outf[o][3], xh[o][3], pp);
                    pp += __shfl_xor(pp, 16, 64);
                    pp += __shfl_xor(pp, 32, 64);
                    lg[o] = pp;
                }
            }
            float sum = 0.f;
            #pragma unroll
            for (int o = 0; o < NO; ++o) { lg[o] = __expf(lg[o]); sum += lg[o]; }
            const float rs = __builtin_amdgcn_rcpf(sum);
            #pragma unroll
            for (int o = 0; o < NO; ++o) {
                const float cc = lg[o] * rs;
                sacc[o][0] = fmaf(cc, xh[o][0], sacc[o][0]);
                sacc[o][1] = fmaf(cc, xh[o][1], sacc[o][1]);
                sacc[o][2] = fmaf(cc, xh[o][2], sacc[o][2]);
                sacc[o][3] = fmaf(cc, xh[o][3], sacc[o][3]);
            }
        }
    }

    iter_epilogue(red, sacc, 1.0f, wv, l, tid,
                  s_part + ((size_t)nc * NBT + bt) * 2560);
}

// ---- reduce chunks + squash (round-10 verbatim) -------------------------
template<int MODE>
__global__ __launch_bounds__(256) void caps_squash(
    const unsigned short* __restrict__ s_part,
    float* __restrict__ outsum,
    float* __restrict__ dout)
{
    __shared__ float sq[256];
    const int bo = blockIdx.x;
    const int t  = threadIdx.x;

    float s = 0.f;
    #pragma unroll 4
    for (int nc = 0; nc < NC; ++nc) {
        __half h = *reinterpret_cast<const __half*>(
            s_part + ((size_t)nc * NBT * NO + bo) * 256 + t);
        s += __half2float(h);
    }

    float n2 = s * s;
    n2 += __shfl_xor(n2, 1, 64);
    n2 += __shfl_xor(n2, 2, 64);       // q-pair reduced
    sq[t] = n2;
    __syncthreads();
    const int base = t & 63;
    n2 = (sq[base] + sq[64 + base]) + (sq[128 + base] + sq[192 + base]);

    const float norm  = sqrtf(n2);
    const float scale = n2 / ((1.f + n2) * (norm + 1e-8f));
    const float v = scale * s;

    if constexpr (MODE == 0) {
        outsum[(size_t)bo * 256 + t] = v;
    } else if constexpr (MODE == 1) {
        outsum[(size_t)bo * 256 + t] += v;
    } else {
        const int bt = bo / NO, o = bo - bt * NO;
        const int b16 = (t >> 2) & 15, hi = t >> 6, q = t & 3;
        dout[((size_t)(bt * BT + b16) * NO + o) * 16 + hi * 4 + q] = v;
    }
}

extern "C" void kernel_launch(void* const* d_in, const int* in_sizes, int n_in,
                              void* d_out, int out_size, void* d_ws, size_t ws_size,
                              hipStream_t stream) {
    const float* x = (const float*)d_in[0];   // [512][1152][8]
    const float* w = (const float*)d_in[1];   // [10][1152][16][8]
    float* out = (float*)d_out;               // [512][10][16]

    unsigned short* s_part = (unsigned short*)d_ws;
    float*          outsum = (float*)(s_part + SPART_H);
    unsigned short* xb     = (unsigned short*)(outsum + OUTSUM_F32);
    unsigned short* wb     = xb + XB_US;      // total ws ~= 17.2 MB

    dim3 gI(NBT * NC), bI(256);               // 768 blocks = 3/CU
    dim3 gS(NBT * NO), bS(256);               // 320 blocks

    caps_f0<<<gI, bI, 0, stream>>>(x, w, xb, wb, s_part);   // cvt + iter0
    caps_squash<0><<<gS, bS, 0, stream>>>(s_part, outsum, nullptr);
    caps_itr<<<gI, bI, 0, stream>>>(xb, wb, outsum, s_part);
    caps_squash<1><<<gS, bS, 0, stream>>>(s_part, outsum, nullptr);
    caps_itr<<<gI, bI, 0, stream>>>(xb, wb, outsum, s_part);
    caps_squash<2><<<gS, bS, 0, stream>>>(s_part, nullptr, out);
}